// Round 8
// baseline (92.374 us; speedup 1.0000x reference)
//
#include <hip/hip_runtime.h>
#include <hip/hip_bf16.h>

#define NE 9
#define NDIM 1024
#define SLOT_ROWS 128       // block M-tile (4 waves x 32 rows)
#define NSLOT_MAX 48        // sum ceil(cnt_e/128) <= 32+9=41; padded to 48 (8|48)
#define SPX (NSLOT_MAX / 8) // 6 slots per XCD

typedef __attribute__((ext_vector_type(8))) short bf16x8;
typedef __attribute__((ext_vector_type(4))) float f32x4;

__device__ __forceinline__ unsigned pack2_bf16(float a, float b) {
    __hip_bfloat162 h = __float22bfloat162_rn(float2{a, b});
    return *reinterpret_cast<unsigned*>(&h);
}

// ------- fused prep: bucket + desc table (block 0) | W,x f32->bf16 (blocks 1+) -----
// xb is NATURAL order (no perm dependency -> race-free); GEMM gathers via perm.
__global__ __launch_bounds__(256)
void prep_kernel(const float* __restrict__ x, const float* __restrict__ W,
                 const int* __restrict__ sidx,
                 unsigned short* __restrict__ xb, unsigned short* __restrict__ Wb,
                 int* __restrict__ perm, int4* __restrict__ desc, int nB) {
    if (blockIdx.x == 0) {
        __shared__ int cnt[NE];
        __shared__ int cur[NE];
        int t = threadIdx.x;
        if (t < NE) cnt[t] = 0;
        __syncthreads();
        for (int i = t; i < nB; i += 256) atomicAdd(&cnt[sidx[i]], 1);
        __syncthreads();
        if (t == 0) {
            int run = 0, s = 0;
            for (int e = 0; e < NE; ++e) {
                cur[e] = run;
                int c = cnt[e];
                for (int m0 = 0; m0 < c; m0 += SLOT_ROWS) {
                    desc[s] = make_int4(e, run + m0, min(SLOT_ROWS, c - m0), 0);
                    ++s;
                }
                run += c;
            }
            for (; s < NSLOT_MAX; ++s) desc[s] = make_int4(-1, 0, 1, 0);
        }
        __syncthreads();
        for (int i = t; i < nB; i += 256) {
            int p = atomicAdd(&cur[sidx[i]], 1);
            perm[p] = i;
        }
    } else {
        const int NW8 = NE * NDIM * (NDIM / 8);
        const int NX8 = nB * (NDIM / 8);
        const int tot = NW8 + NX8;
        const int stride = (gridDim.x - 1) * 256;
        for (int u = (blockIdx.x - 1) * 256 + threadIdx.x; u < tot; u += stride) {
            const float4* src;
            uint4* dst;
            if (u < NW8) {
                src = (const float4*)W + 2 * (size_t)u;
                dst = (uint4*)Wb + u;
            } else {
                size_t v = (size_t)(u - NW8);
                src = (const float4*)x + 2 * v;
                dst = (uint4*)xb + v;
            }
            float4 a = src[0], c = src[1];
            uint4 o;
            o.x = pack2_bf16(a.x, a.y);
            o.y = pack2_bf16(a.z, a.w);
            o.z = pack2_bf16(c.x, c.y);
            o.w = pack2_bf16(c.z, c.w);
            *dst = o;
        }
    }
}

// ------- barrier-free register GEMM ------------------------------------------------
// Block = 4 waves stacked in M (128 rows x 64 cols); wave = 32x64 output tile.
// No LDS, no __syncthreads. Fragment loads are 1 dwordx4/lane straight from global
// (16 full cache lines per wave-fragment). Register double-buffer, static names.
__global__ __launch_bounds__(256, 4)
void gemm_reg_kernel(const unsigned short* __restrict__ xb,
                     const unsigned short* __restrict__ Wb,
                     const float* __restrict__ bias,
                     const int* __restrict__ perm,
                     const int4* __restrict__ desc,
                     float* __restrict__ out) {
    // static bijective XCD map: XCD = b&7 owns SPX contiguous slots x all 16 N-tiles
    const int b    = blockIdx.x;
    const int xcd  = b & 7;
    const int loc  = b >> 3;                    // 0..95
    const int slot = xcd * SPX + (loc >> 4);
    const int n    = loc & 15;
    const int4 d   = desc[slot];
    if (d.x < 0) return;
    const int e = d.x, rowstart = d.y, rcnt = d.z;
    const int n0 = n * 64;

    const int t    = threadIdx.x;
    const int wave = t >> 6;
    const int lane = t & 63;
    const int fr   = lane & 15;
    const int fq   = lane >> 4;
    const int ws   = wave * 32;                 // wave's row offset within slot

    // per-lane operand row pointers (computed once; k advances by element offset)
    const unsigned short* ap0;
    const unsigned short* ap1;
    {
        int lm0 = ws + fr;      if (lm0 >= rcnt) lm0 = rcnt - 1;
        int lm1 = ws + 16 + fr; if (lm1 >= rcnt) lm1 = rcnt - 1;
        ap0 = xb + (size_t)perm[rowstart + lm0] * NDIM + fq * 8;
        ap1 = xb + (size_t)perm[rowstart + lm1] * NDIM + fq * 8;
    }
    const unsigned short* bp0 = Wb + ((size_t)e * NDIM + n0 +      fr) * NDIM + fq * 8;
    const unsigned short* bp1 = bp0 + (size_t)16 * NDIM;
    const unsigned short* bp2 = bp0 + (size_t)32 * NDIM;
    const unsigned short* bp3 = bp0 + (size_t)48 * NDIM;

    f32x4 acc[2][4];
#pragma unroll
    for (int i = 0; i < 2; ++i)
#pragma unroll
        for (int k = 0; k < 4; ++k) acc[i][k] = (f32x4)(0.0f);

    bf16x8 a0_0, a0_1, b0_0, b0_1, b0_2, b0_3;   // buffer 0
    bf16x8 a1_0, a1_1, b1_0, b1_1, b1_2, b1_3;   // buffer 1

#define LD0(KK)                                                    \
    do {                                                           \
        a0_0 = *(const bf16x8*)(ap0 + (KK));                       \
        a0_1 = *(const bf16x8*)(ap1 + (KK));                       \
        b0_0 = *(const bf16x8*)(bp0 + (KK));                       \
        b0_1 = *(const bf16x8*)(bp1 + (KK));                       \
        b0_2 = *(const bf16x8*)(bp2 + (KK));                       \
        b0_3 = *(const bf16x8*)(bp3 + (KK));                       \
    } while (0)
#define LD1(KK)                                                    \
    do {                                                           \
        a1_0 = *(const bf16x8*)(ap0 + (KK));                       \
        a1_1 = *(const bf16x8*)(ap1 + (KK));                       \
        b1_0 = *(const bf16x8*)(bp0 + (KK));                       \
        b1_1 = *(const bf16x8*)(bp1 + (KK));                       \
        b1_2 = *(const bf16x8*)(bp2 + (KK));                       \
        b1_3 = *(const bf16x8*)(bp3 + (KK));                       \
    } while (0)
#define MM(A0, A1, B0, B1, B2, B3)                                             \
    do {                                                                       \
        acc[0][0] = __builtin_amdgcn_mfma_f32_16x16x32_bf16(A0, B0, acc[0][0], 0, 0, 0); \
        acc[0][1] = __builtin_amdgcn_mfma_f32_16x16x32_bf16(A0, B1, acc[0][1], 0, 0, 0); \
        acc[0][2] = __builtin_amdgcn_mfma_f32_16x16x32_bf16(A0, B2, acc[0][2], 0, 0, 0); \
        acc[0][3] = __builtin_amdgcn_mfma_f32_16x16x32_bf16(A0, B3, acc[0][3], 0, 0, 0); \
        acc[1][0] = __builtin_amdgcn_mfma_f32_16x16x32_bf16(A1, B0, acc[1][0], 0, 0, 0); \
        acc[1][1] = __builtin_amdgcn_mfma_f32_16x16x32_bf16(A1, B1, acc[1][1], 0, 0, 0); \
        acc[1][2] = __builtin_amdgcn_mfma_f32_16x16x32_bf16(A1, B2, acc[1][2], 0, 0, 0); \
        acc[1][3] = __builtin_amdgcn_mfma_f32_16x16x32_bf16(A1, B3, acc[1][3], 0, 0, 0); \
    } while (0)

    LD0(0);
#pragma unroll
    for (int kk = 0; kk < NDIM; kk += 64) {
        LD1(kk + 32);                          // always valid: NDIM % 64 == 0
        MM(a0_0, a0_1, b0_0, b0_1, b0_2, b0_3);
        if (kk + 64 < NDIM) LD0(kk + 64);
        MM(a1_0, a1_1, b1_0, b1_1, b1_2, b1_3);
    }
#undef LD0
#undef LD1
#undef MM

    // ---- epilogue: bias add + scatter store via perm ----
    float bl[4];
#pragma unroll
    for (int nf = 0; nf < 4; ++nf)
        bl[nf] = bias[e * NDIM + n0 + nf * 16 + fr];

#pragma unroll
    for (int mf = 0; mf < 2; ++mf) {
#pragma unroll
        for (int jr = 0; jr < 4; ++jr) {
            int lm = ws + mf * 16 + fq * 4 + jr;
            if (lm < rcnt) {
                int grow = perm[rowstart + lm];
                float* orow = out + (size_t)grow * NDIM;
#pragma unroll
                for (int nf = 0; nf < 4; ++nf)
                    orow[n0 + nf * 16 + fr] = acc[mf][nf][jr] + bl[nf];
            }
        }
    }
}

// ---------------- tiny correct fallback (ws too small; not expected) --------------
__global__ void naive_kernel(const float* __restrict__ x, const float* __restrict__ W,
                             const float* __restrict__ bias,
                             const int* __restrict__ sidx, float* __restrict__ out,
                             int nB) {
    int i = blockIdx.x;
    int c = threadIdx.x + (blockIdx.y << 8);
    if (i >= nB || c >= NDIM) return;
    int e = sidx[i];
    const float* wrow = W + ((size_t)e * NDIM + c) * NDIM;
    const float* xr = x + (size_t)i * NDIM;
    float s = bias[e * NDIM + c];
    for (int k = 0; k < NDIM; ++k) s += xr[k] * wrow[k];
    out[(size_t)i * NDIM + c] = s;
}

extern "C" void kernel_launch(void* const* d_in, const int* in_sizes, int n_in,
                              void* d_out, int out_size, void* d_ws, size_t ws_size,
                              hipStream_t stream) {
    const float* x    = (const float*)d_in[0];
    const float* W    = (const float*)d_in[1];
    const float* bias = (const float*)d_in[2];
    const int*   sidx = (const int*)d_in[3];
    float*       out  = (float*)d_out;

    const int nB = in_sizes[3];   // 4096

    char* wsb = (char*)d_ws;
    size_t p_desc = (size_t)nB * 4;
    size_t p_xb   = ((p_desc + NSLOT_MAX * 16 + 511) / 512) * 512;
    size_t p_wb   = p_xb + (size_t)nB * NDIM * 2;
    size_t need   = p_wb + (size_t)NE * NDIM * NDIM * 2;

    if (ws_size < need) {
        dim3 g(nB, NDIM / 256);
        naive_kernel<<<g, 256, 0, stream>>>(x, W, bias, sidx, out, nB);
        return;
    }

    int*  perm = (int*)wsb;
    int4* desc = (int4*)(wsb + p_desc);
    unsigned short* xb = (unsigned short*)(wsb + p_xb);
    unsigned short* Wb = (unsigned short*)(wsb + p_wb);

    prep_kernel<<<1024, 256, 0, stream>>>(x, W, sidx, xb, Wb, perm, desc, nB);

    gemm_reg_kernel<<<NSLOT_MAX * 16, 256, 0, stream>>>(xb, Wb, bias, perm, desc, out);
}

// Round 9
// 44.031 us; speedup vs baseline: 2.0979x; 2.0979x over previous
//
#include <hip/hip_runtime.h>
#include <hip/hip_bf16.h>

#define NE 9
#define NDIM 1024
#define BM 128
#define BN 128
#define BK 64
#define NT (NDIM / BK)      // 16
#define NSLOT_MAX 48        // sum ceil(cnt_e/128) <= 32+9=41; padded to 48 (8|48)
#define SPX (NSLOT_MAX / 8) // 6 slots per XCD

typedef __attribute__((ext_vector_type(8))) short bf16x8;
typedef __attribute__((ext_vector_type(4))) float f32x4;

__device__ __forceinline__ unsigned pack2_bf16(float a, float b) {
    __hip_bfloat162 h = __float22bfloat162_rn(float2{a, b});
    return *reinterpret_cast<unsigned*>(&h);
}

__device__ __forceinline__ void gload_lds16(const void* g, void* l) {
    __builtin_amdgcn_global_load_lds(
        (const __attribute__((address_space(1))) unsigned int*)g,
        (__attribute__((address_space(3))) unsigned int*)l, 16, 0, 0);
}

// ------- fused prep: bucket + desc table (block 0) | W,x f32->bf16 (blocks 1+) -----
__global__ __launch_bounds__(256)
void prep_kernel(const float* __restrict__ x, const float* __restrict__ W,
                 const int* __restrict__ sidx,
                 unsigned short* __restrict__ xb, unsigned short* __restrict__ Wb,
                 int* __restrict__ perm, int4* __restrict__ desc, int nB) {
    if (blockIdx.x == 0) {
        __shared__ int cnt[NE];
        __shared__ int cur[NE];
        int t = threadIdx.x;
        if (t < NE) cnt[t] = 0;
        __syncthreads();
        for (int i = t; i < nB; i += 256) atomicAdd(&cnt[sidx[i]], 1);
        __syncthreads();
        if (t == 0) {
            int run = 0, s = 0;
            for (int e = 0; e < NE; ++e) {
                cur[e] = run;
                int c = cnt[e];
                for (int m0 = 0; m0 < c; m0 += BM) {
                    desc[s] = make_int4(e, run + m0, min(BM, c - m0), 0);
                    ++s;
                }
                run += c;
            }
            for (; s < NSLOT_MAX; ++s) desc[s] = make_int4(-1, 0, 1, 0);
        }
        __syncthreads();
        for (int i = t; i < nB; i += 256) {
            int p = atomicAdd(&cur[sidx[i]], 1);
            perm[p] = i;
        }
    } else {
        const int NW8 = NE * NDIM * (NDIM / 8);
        const int NX8 = nB * (NDIM / 8);
        const int tot = NW8 + NX8;
        const int stride = (gridDim.x - 1) * 256;
        for (int u = (blockIdx.x - 1) * 256 + threadIdx.x; u < tot; u += stride) {
            const float4* src;
            uint4* dst;
            if (u < NW8) {
                src = (const float4*)W + 2 * (size_t)u;
                dst = (uint4*)Wb + u;
            } else {
                size_t v = (size_t)(u - NW8);
                src = (const float4*)x + 2 * v;
                dst = (uint4*)xb + v;
            }
            float4 a = src[0], c = src[1];
            uint4 o;
            o.x = pack2_bf16(a.x, a.y);
            o.y = pack2_bf16(a.z, a.w);
            o.z = pack2_bf16(c.x, c.y);
            o.w = pack2_bf16(c.z, c.w);
            *dst = o;
        }
    }
}

// ------- bf16 grouped GEMM: 128x128 tile, 4 waves of 64x64, 64 KB LDS -------------
// Traffic-optimal within occupancy limits: 32 KB staged per 128x128x64 step
// (0.0156 B/output/K vs 0.0234 at 64x128). r4-proven 2-buffer gload_lds pipeline,
// pre-swizzled source + swizzled ds_read (0 bank conflicts).
__global__ __launch_bounds__(256, 2)
void gemm_kernel(const unsigned short* __restrict__ xb,
                 const unsigned short* __restrict__ Wb,
                 const float* __restrict__ bias,
                 const int* __restrict__ perm,
                 const int4* __restrict__ desc,
                 float* __restrict__ out) {
    // bijective XCD map: XCD = b&7 owns SPX contiguous slots; a slot's 8 N-tiles
    // are CONSECUTIVE blocks on that XCD -> A panel + expert W panel L2-resident.
    const int b    = blockIdx.x;
    const int xcd  = b & 7;
    const int loc  = b >> 3;                 // 0..47
    const int slot = xcd * SPX + (loc >> 3);
    const int n    = loc & 7;
    const int4 d   = desc[slot];
    if (d.x < 0) return;
    const int e = d.x, rowstart = d.y, rcnt = d.z;
    const int n0 = n * BN;

    // ushort idx: A bufs @ {0, 8192}, B bufs @ 16384 + {0, 8192}; 64 KB total
    __shared__ __align__(16) unsigned short lds[32768];

    const int t    = threadIdx.x;
    const int wave = t >> 6;
    const int lane = t & 63;
    const int fr   = lane & 15;
    const int fq   = lane >> 4;
    const int wr   = (wave >> 1) * 64;   // wave M-origin
    const int wc   = (wave & 1) * 64;    // wave N-origin
    const int xr   = fr & 7;             // read-side swizzle key

    // staging: 8 lanes per row; thread covers rows {i*32 + srow} i=0..3
    const int srow = t >> 3;                       // 0..31
    const int scol = ((t & 7) ^ (srow & 7)) * 8;   // pre-swizzled col (key = row&7)

    const unsigned short* asrc[4];
#pragma unroll
    for (int i = 0; i < 4; ++i) {
        int lm = i * 32 + srow;
        if (lm >= rcnt) lm = rcnt - 1;             // clamp; masked at store
        asrc[i] = xb + (size_t)perm[rowstart + lm] * NDIM + scol;
    }
    const unsigned short* bsrc = Wb + ((size_t)e * NDIM + n0 + srow) * NDIM + scol;

#define STAGE(BUF, K0)                                                         \
    do {                                                                       \
        _Pragma("unroll")                                                      \
        for (int i = 0; i < 4; ++i) {                                          \
            gload_lds16(asrc[i] + (K0),                                        \
                        &lds[(BUF) * 8192 + i * 2048 + wave * 512]);           \
            gload_lds16(bsrc + (size_t)i * 32 * NDIM + (K0),                   \
                        &lds[16384 + (BUF) * 8192 + i * 2048 + wave * 512]);   \
        }                                                                      \
    } while (0)

    f32x4 acc[4][4];
#pragma unroll
    for (int i = 0; i < 4; ++i)
#pragma unroll
        for (int k = 0; k < 4; ++k) acc[i][k] = (f32x4)(0.0f);

    STAGE(0, 0);
    __syncthreads();

    for (int tt = 0; tt < NT; ++tt) {
        const int cur = tt & 1;
        // issue next tile's DMA first; it flies under this tile's compute
        if (tt + 1 < NT) STAGE(cur ^ 1, (tt + 1) * BK);

        const int abase = cur * 8192;
        const int bbase = 16384 + cur * 8192;
#pragma unroll
        for (int kk = 0; kk < 2; ++kk) {
            const int cs = ((kk * 4 + fq) ^ xr) * 8;
            bf16x8 af[4], bfv[4];
#pragma unroll
            for (int mf = 0; mf < 4; ++mf)
                af[mf] = *reinterpret_cast<const bf16x8*>(
                    &lds[abase + (wr + mf * 16 + fr) * 64 + cs]);
#pragma unroll
            for (int nf = 0; nf < 4; ++nf)
                bfv[nf] = *reinterpret_cast<const bf16x8*>(
                    &lds[bbase + (wc + nf * 16 + fr) * 64 + cs]);
#pragma unroll
            for (int mf = 0; mf < 4; ++mf)
#pragma unroll
                for (int nf = 0; nf < 4; ++nf)
                    acc[mf][nf] = __builtin_amdgcn_mfma_f32_16x16x32_bf16(
                        af[mf], bfv[nf], acc[mf][nf], 0, 0, 0);
        }
        __syncthreads();   // drains stage loads + protects buffer reuse
    }
#undef STAGE

    // ---- epilogue: bias add + scatter store via perm ----
    float bl[4];
#pragma unroll
    for (int nf = 0; nf < 4; ++nf)
        bl[nf] = bias[e * NDIM + n0 + wc + nf * 16 + fr];

#pragma unroll
    for (int mf = 0; mf < 4; ++mf) {
#pragma unroll
        for (int jr = 0; jr < 4; ++jr) {
            int lm = wr + mf * 16 + fq * 4 + jr;
            if (lm < rcnt) {
                int grow = perm[rowstart + lm];
                float* orow = out + (size_t)grow * NDIM;
#pragma unroll
                for (int nf = 0; nf < 4; ++nf)
                    orow[n0 + wc + nf * 16 + fr] = acc[mf][nf][jr] + bl[nf];
            }
        }
    }
}

// ---------------- tiny correct fallback (ws too small; not expected) --------------
__global__ void naive_kernel(const float* __restrict__ x, const float* __restrict__ W,
                             const float* __restrict__ bias,
                             const int* __restrict__ sidx, float* __restrict__ out,
                             int nB) {
    int i = blockIdx.x;
    int c = threadIdx.x + (blockIdx.y << 8);
    if (i >= nB || c >= NDIM) return;
    int e = sidx[i];
    const float* wrow = W + ((size_t)e * NDIM + c) * NDIM;
    const float* xr = x + (size_t)i * NDIM;
    float s = bias[e * NDIM + c];
    for (int k = 0; k < NDIM; ++k) s += xr[k] * wrow[k];
    out[(size_t)i * NDIM + c] = s;
}

extern "C" void kernel_launch(void* const* d_in, const int* in_sizes, int n_in,
                              void* d_out, int out_size, void* d_ws, size_t ws_size,
                              hipStream_t stream) {
    const float* x    = (const float*)d_in[0];
    const float* W    = (const float*)d_in[1];
    const float* bias = (const float*)d_in[2];
    const int*   sidx = (const int*)d_in[3];
    float*       out  = (float*)d_out;

    const int nB = in_sizes[3];   // 4096

    char* wsb = (char*)d_ws;
    size_t p_desc = (size_t)nB * 4;
    size_t p_xb   = ((p_desc + NSLOT_MAX * 16 + 511) / 512) * 512;
    size_t p_wb   = p_xb + (size_t)nB * NDIM * 2;
    size_t need   = p_wb + (size_t)NE * NDIM * NDIM * 2;

    if (ws_size < need) {
        dim3 g(nB, NDIM / 256);
        naive_kernel<<<g, 256, 0, stream>>>(x, W, bias, sidx, out, nB);
        return;
    }

    int*  perm = (int*)wsb;
    int4* desc = (int4*)(wsb + p_desc);
    unsigned short* xb = (unsigned short*)(wsb + p_xb);
    unsigned short* Wb = (unsigned short*)(wsb + p_wb);

    prep_kernel<<<1024, 256, 0, stream>>>(x, W, sidx, xb, Wb, perm, desc, nB);

    gemm_kernel<<<NSLOT_MAX * 8, 256, 0, stream>>>(xb, Wb, bias, perm, desc, out);
}